// Round 4
// baseline (577.429 us; speedup 1.0000x reference)
//
#include <hip/hip_runtime.h>
#include <math.h>

// Problem constants (fixed by setup_inputs)
#define M_TOK 16384   // B*T
#define DIM   256     // D (=K)
#define VOC   8192    // V (=N)

// GEMM tiling (R2-proven 128x128 structure, BK=64 as two 32-slices)
#define BM 128
#define BN 128
#define NBLK_N (VOC / BN)   // 64
// hi-only GEMM: d2 gap error sigma ~0.11-0.16 (bf16 RN 2^-8, K=256);
// threshold = ~6-7 sigma. Rows with noisy top-2 gap < GAP_EPS go to exact
// fp32 rescue (~7-11% expected).
#define GAP_EPS 1.0f

typedef unsigned short u16;
typedef unsigned long long u64;
typedef __attribute__((ext_vector_type(8))) __bf16 bf16x8;
typedef __attribute__((ext_vector_type(4))) float f32x4;

// ---- workspace layout (float-element offsets) ------------------------------
#define WS_ESQ      0                     // [8192]
#define WS_FLAGROWS 24576                 // [16384] int
#define WS_CANDV    40960                 // [64][16384] f32
#define WS_CANDI    1089536               // [64][16384] int
#define WS_CANDS    2138112               // [64][16384] f32
#define WS_XHI      3186688               // [16384*256] bf16 (2097152 f32 slots)
#define WS_XLO      5283840               // (unused now)
#define WS_EHI      7380992               // [8192*256] bf16 (1048576 slots)
#define WS_ELO      8429568               // (unused now)
#define WS_COUNTS   9478144               // [8192]
#define WS_SUMS     9486336               // [8192*256]
#define WS_FLAGCNT  11583488              // [16] int
// rescueBuf [16384] u64 aliases Xhi (dead after mfma_argmin; reduce writes it)
#define WS_RESCUE   WS_XHI
#define WS_ZERO_OFF_BYTES ((size_t)WS_COUNTS * 4)
#define WS_ZERO_BYTES     ((size_t)(8192 + 2097152 + 16) * 4)

// ---- out layout (float-element offsets): quantize, codes, new_embed, new_cs, new_ea
#define OUT_Q   0
#define OUT_C   4194304
#define OUT_NE  4210688
#define OUT_NCS 6307840
#define OUT_NEA 6316032

__device__ inline u16 f2bf_rn(float x) {
    unsigned u = __float_as_uint(x);
    unsigned r = u + 0x7FFFu + ((u >> 16) & 1u);   // round-to-nearest-even
    return (u16)(r >> 16);
}
__device__ inline unsigned f2key(float f) {          // order-preserving uint
    unsigned b = __float_as_uint(f);
    return (b & 0x80000000u) ? ~b : (b | 0x80000000u);
}

// ---------------------------------------------------------------------------
// prep: round X,E to bf16 (hi only); compute esq from fp32 originals.
__global__ __launch_bounds__(256) void prep_kernel(
    const float* __restrict__ X, const float* __restrict__ E,
    u16* __restrict__ Xhi, u16* __restrict__ Ehi,
    float* __restrict__ esq)
{
    int row  = blockIdx.x * 4 + (threadIdx.x >> 6);
    int lane = threadIdx.x & 63;
    bool isX = row < M_TOK;
    int r = isX ? row : row - M_TOK;
    const float* src = isX ? X + (size_t)row * DIM : E + (size_t)r * DIM;
    float4 v = ((const float4*)src)[lane];

    ushort4 h;
    h.x = f2bf_rn(v.x); h.y = f2bf_rn(v.y);
    h.z = f2bf_rn(v.z); h.w = f2bf_rn(v.w);
    u16* dh = isX ? Xhi : Ehi;
    *(ushort4*)&dh[(size_t)r * DIM + lane * 4] = h;

    if (!isX) {
        float s = v.x * v.x + v.y * v.y + v.z * v.z + v.w * v.w;
        #pragma unroll
        for (int o = 1; o < 64; o <<= 1) s += __shfl_xor(s, o, 64);
        if (lane == 0) esq[r] = s;
    }
}

// ---------------------------------------------------------------------------
// mfma_argmin (hi-only, R2-proven 128x128 structure, BK=64 per barrier-pair):
// per K-step, 4 staged 8KB subtiles = A[k0:k0+32), A[k0+32:k0+64), same for B;
// 32 MFMAs per step, 4 steps (half the barrier drains of the BK=32 version).
// dot = bf16(x).bf16(e); epilogue tracks per-row top-2 of (esq[n] - 2*dot);
// rows with gap < GAP_EPS are re-solved exactly in rescue_kernel.
// LDS staged via global_load_lds(16B) with XOR chunk swizzle (DMA forbids
// padding; swizzle keeps frag ds_read_b128 at <=2-way bank alias = free).
// Epilogue smB/I/S alias the dead tiles buffer -> LDS_Block_Size = 32768.
__global__ __launch_bounds__(256, 2) void mfma_argmin_kernel(
    const u16* __restrict__ Xhi, const u16* __restrict__ Ehi,
    const float* __restrict__ esq,
    float* __restrict__ candV, int* __restrict__ candI, float* __restrict__ candS)
{
    __shared__ __align__(16) char tiles[4 * 8192];   // A_k0, A_k1, B_k0, B_k1

    const int tid = threadIdx.x;
    const int w = tid >> 6, l = tid & 63;
    const int wy = w >> 1, wx = w & 1;
    const int m0 = blockIdx.x * BM;
    const int n0 = blockIdx.y * BN;

    f32x4 acc[4][4];
    #pragma unroll
    for (int i = 0; i < 4; ++i)
        #pragma unroll
        for (int j = 0; j < 4; ++j) acc[i][j] = (f32x4)0.0f;

    // staging: wave w stages subtile w (0=A_k0 1=A_k1 2=B_k0 3=B_k1)
    const u16* gbase = (w < 2) ? Xhi : Ehi;
    const int row0   = (w < 2) ? m0 : n0;
    const int koff   = (w & 1) * 32;                 // k-half within the 64-slice
    const int swz_c = (l & 3) ^ ((l >> 3) & 3);
    const u16* gsrc0 = gbase + (size_t)(row0 + (l >> 2)) * DIM + koff + swz_c * 8;
    char* ltile = tiles + w * 8192;

    const int frow = l & 15, fq = l >> 4;
    const int fs = ((fq ^ ((frow >> 1) & 3)) * 16);
    const char* a0P = tiles + 0 * 8192 + (wy * 64 + frow) * 64 + fs;
    const char* a1P = tiles + 1 * 8192 + (wy * 64 + frow) * 64 + fs;
    const char* b0P = tiles + 2 * 8192 + (wx * 64 + frow) * 64 + fs;
    const char* b1P = tiles + 3 * 8192 + (wx * 64 + frow) * 64 + fs;

    for (int ks = 0; ks < 4; ++ks) {
        const int k0 = ks * 64;
        __syncthreads();
        #pragma unroll
        for (int i = 0; i < 8; ++i) {
            __builtin_amdgcn_global_load_lds(
                (const __attribute__((address_space(1))) unsigned int*)(gsrc0 + (size_t)i * 16 * DIM + k0),
                (__attribute__((address_space(3))) unsigned int*)(ltile + i * 1024),
                16, 0, 0);
        }
        __syncthreads();

        bf16x8 a0[4], a1[4];
        #pragma unroll
        for (int mt = 0; mt < 4; ++mt) {
            a0[mt] = *(const bf16x8*)(a0P + mt * 1024);
            a1[mt] = *(const bf16x8*)(a1P + mt * 1024);
        }
        #pragma unroll
        for (int nt = 0; nt < 4; ++nt) {
            bf16x8 b0 = *(const bf16x8*)(b0P + nt * 1024);
            bf16x8 b1 = *(const bf16x8*)(b1P + nt * 1024);
            #pragma unroll
            for (int mt = 0; mt < 4; ++mt) {
                acc[mt][nt] = __builtin_amdgcn_mfma_f32_16x16x32_bf16(a0[mt], b0, acc[mt][nt], 0, 0, 0);
                acc[mt][nt] = __builtin_amdgcn_mfma_f32_16x16x32_bf16(a1[mt], b1, acc[mt][nt], 0, 0, 0);
            }
        }
    }

    // tiles are dead from here; re-use for the cross-wave reduce arrays
    __syncthreads();
    float* smB = (float*)tiles;            // [2][128]
    int*   smI = (int*)(tiles + 1024);     // [2][128]
    float* smS = (float*)(tiles + 2048);   // [2][128]

    // epilogue: per-row top-2 argmin of val = esq[n] - 2*dot
    float eq[4];
    #pragma unroll
    for (int nt = 0; nt < 4; ++nt) eq[nt] = esq[n0 + wx * 64 + nt * 16 + frow];

    #pragma unroll
    for (int mt = 0; mt < 4; ++mt) {
        #pragma unroll
        for (int r = 0; r < 4; ++r) {
            float b = 3.4e38f, s = 3.4e38f;
            int bi = 0;
            #pragma unroll
            for (int nt = 0; nt < 4; ++nt) {
                float v = fmaf(-2.0f, acc[mt][nt][r], eq[nt]);
                int col = n0 + wx * 64 + nt * 16 + frow;
                if (v < b) { s = b; b = v; bi = col; }
                else if (v < s) s = v;
            }
            #pragma unroll
            for (int o = 1; o < 16; o <<= 1) {
                float ob = __shfl_xor(b, o, 64);
                int   oi = __shfl_xor(bi, o, 64);
                float os = __shfl_xor(s, o, 64);
                bool take = (ob < b) || (ob == b && oi < bi);
                float keep = take ? b : ob;
                b  = take ? ob : b;
                bi = take ? oi : bi;
                s  = fminf(fminf(s, os), keep);
            }
            if (frow == 0) {
                int m_loc = wy * 64 + mt * 16 + fq * 4 + r;
                smB[wx * 128 + m_loc] = b;
                smI[wx * 128 + m_loc] = bi;
                smS[wx * 128 + m_loc] = s;
            }
        }
    }
    __syncthreads();
    if (tid < 128) {
        float b0 = smB[tid],       b1 = smB[128 + tid];
        int   i0 = smI[tid],       i1 = smI[128 + tid];
        float s0 = smS[tid],       s1 = smS[128 + tid];
        bool take = (b1 < b0);                 // tie -> wave 0 (lower cols)
        float b = take ? b1 : b0;
        int  bi = take ? i1 : i0;
        float s = fminf(fminf(s0, s1), take ? b0 : b1);
        size_t e = (size_t)blockIdx.y * M_TOK + (m0 + tid);
        candV[e] = b; candI[e] = bi; candS[e] = s;
    }
}

// ---------------------------------------------------------------------------
// reduce: fold 64 n-block candidates per row. Batched-8 independent candV
// loads; candS/candI read lazily only for the winning block (true global
// second = min(2nd-min over candV, candS[e*])). Packs (key|idx) u64 into
// rescueBuf; flagged rows get ~0 sentinel for rescue's atomicMin.
__global__ __launch_bounds__(64) void reduce_kernel(
    const float* __restrict__ candV, const int* __restrict__ candI,
    const float* __restrict__ candS,
    int* __restrict__ flagCnt, int* __restrict__ flagRows,
    u64* __restrict__ rescueBuf)
{
    int row = blockIdx.x * 64 + threadIdx.x;
    float best = 3.4e38f, second = 3.4e38f;
    int ebest = 0;
    #pragma unroll
    for (int e0 = 0; e0 < NBLK_N; e0 += 8) {
        float v[8];
        #pragma unroll
        for (int j = 0; j < 8; ++j) v[j] = candV[(size_t)(e0 + j) * M_TOK + row];
        #pragma unroll
        for (int j = 0; j < 8; ++j) {
            if (v[j] < best) { second = best; best = v[j]; ebest = e0 + j; }
            else second = fminf(second, v[j]);
        }
    }
    int bi = candI[(size_t)ebest * M_TOK + row];
    second = fminf(second, candS[(size_t)ebest * M_TOK + row]);
    u64 pk = ((u64)f2key(best) << 32) | (unsigned)bi;
    if (second - best < GAP_EPS) {
        pk = ~0ull;
        int k = atomicAdd(flagCnt, 1);
        flagRows[k] = row;
    }
    rescueBuf[row] = pk;
}

// ---------------------------------------------------------------------------
// rescue: exact fp32 argmin for flagged rows. BATCHED: each work item is
// (group of 8 flagged rows, 256-code chunk). xr[8][256] staged in LDS; the
// inner fma reads xr with wave-uniform addresses (broadcast). Winner via
// per-wave u64 shuffle-min then one atomicMin per (wave,row).
__global__ __launch_bounds__(256) void rescue_kernel(
    const float* __restrict__ X, const float* __restrict__ E,
    const float* __restrict__ esq,
    const int* __restrict__ flagCnt, const int* __restrict__ flagRows,
    u64* __restrict__ rescueBuf)
{
    __shared__ float xr[8][DIM];
    __shared__ int rowids[8];
    const int nflag = flagCnt[0];
    const int ngroups = (nflag + 7) >> 3;
    const int nwork = ngroups * 32;
    const int lane = threadIdx.x & 63;

    for (int wk = blockIdx.x; wk < nwork; wk += gridDim.x) {
        const int g = wk >> 5, chunk = wk & 31;
        __syncthreads();                       // protect xr/rowids reuse
        if (threadIdx.x < 8) {
            int idx = g * 8 + threadIdx.x;
            rowids[threadIdx.x] = (idx < nflag) ? flagRows[idx] : -1;
        }
        {
            int i = threadIdx.x >> 5;          // row slot 0..7
            int idx = g * 8 + i;
            int row = flagRows[(idx < nflag) ? idx : (nflag - 1)];
            const float4* src = (const float4*)(X + (size_t)row * DIM);
            int c4 = (threadIdx.x & 31) * 2;
            ((float4*)xr[i])[c4]     = src[c4];
            ((float4*)xr[i])[c4 + 1] = src[c4 + 1];
        }
        __syncthreads();

        const int c = (chunk << 8) + threadIdx.x;
        const float4* er = (const float4*)(E + (size_t)c * DIM);
        float dot[8];
        #pragma unroll
        for (int i = 0; i < 8; ++i) dot[i] = 0.0f;
        #pragma unroll 4
        for (int k = 0; k < DIM / 4; ++k) {
            float4 e4 = er[k];
            #pragma unroll
            for (int i = 0; i < 8; ++i) {
                float4 x4 = ((const float4*)xr[i])[k];   // wave-uniform: broadcast
                dot[i] = fmaf(x4.x, e4.x, dot[i]);
                dot[i] = fmaf(x4.y, e4.y, dot[i]);
                dot[i] = fmaf(x4.z, e4.z, dot[i]);
                dot[i] = fmaf(x4.w, e4.w, dot[i]);
            }
        }
        float eq = esq[c];
        #pragma unroll
        for (int i = 0; i < 8; ++i) {
            float v = fmaf(-2.0f, dot[i], eq);
            u64 pk = ((u64)f2key(v) << 32) | (unsigned)c;
            #pragma unroll
            for (int o = 1; o < 64; o <<= 1) {
                u64 other = __shfl_xor(pk, o, 64);
                pk = (other < pk) ? other : pk;
            }
            if (lane == 0 && g * 8 + i < nflag)
                atomicMin(&rescueBuf[rowids[i]], pk);
        }
    }
}

// ---------------------------------------------------------------------------
// assign: unpack code, write codes + quantize (STE), scatter counts/sums.
__global__ __launch_bounds__(256) void assign_kernel(
    const float* __restrict__ X, const float* __restrict__ E,
    const u64* __restrict__ rescueBuf,
    float* __restrict__ out_q, float* __restrict__ out_codes,
    float* __restrict__ counts, float* __restrict__ sums)
{
    int t = blockIdx.x * 4 + (threadIdx.x >> 6);
    int lane = threadIdx.x & 63;
    int code = (int)(unsigned)(rescueBuf[t] & 0xFFFFFFFFull);
    if (lane == 0) {
        out_codes[t] = (float)code;
        atomicAdd(&counts[code], 1.0f);
    }
    float4 x = *(const float4*)&X[(size_t)t * DIM + lane * 4];
    float4 e = *(const float4*)&E[(size_t)code * DIM + lane * 4];
    float4 q;
    q.x = x.x + (e.x - x.x);
    q.y = x.y + (e.y - x.y);
    q.z = x.z + (e.z - x.z);
    q.w = x.w + (e.w - x.w);
    *(float4*)&out_q[(size_t)t * DIM + lane * 4] = q;
    float* s = &sums[(size_t)code * DIM + lane * 4];
    atomicAdd(s + 0, x.x);
    atomicAdd(s + 1, x.y);
    atomicAdd(s + 2, x.z);
    atomicAdd(s + 3, x.w);
}

// ---------------------------------------------------------------------------
__global__ __launch_bounds__(256) void finalize_kernel(
    const float* __restrict__ cs, const float* __restrict__ ea,
    const float* __restrict__ counts, const float* __restrict__ sums,
    float* __restrict__ out_embed, float* __restrict__ out_cs,
    float* __restrict__ out_ea)
{
    int vd = blockIdx.x * 256 + threadIdx.x;
    int v = vd >> 8, d = vd & 255;
    float cnt = counts[v];
    float ncs = cs[v] * 0.99f + cnt * 0.01f;
    float cb  = sums[vd] * (1.0f / 2048.0f);
    float nea = ea[vd] * 0.99f + cb * 0.01f;
    out_ea[vd] = nea;
    out_embed[vd] = nea / (ncs + 1e-5f);
    if (d == 0) out_cs[v] = ncs;
}

// ---------------------------------------------------------------------------
extern "C" void kernel_launch(void* const* d_in, const int* in_sizes, int n_in,
                              void* d_out, int out_size, void* d_ws, size_t ws_size,
                              hipStream_t stream)
{
    const float* input     = (const float*)d_in[0];
    const float* embed     = (const float*)d_in[1];
    const float* cluster   = (const float*)d_in[2];
    const float* embed_avg = (const float*)d_in[3];

    float* out = (float*)d_out;
    float* ws  = (float*)d_ws;

    float* esq      = ws + WS_ESQ;
    int*   flagRows = (int*)(ws + WS_FLAGROWS);
    float* candV    = ws + WS_CANDV;
    int*   candI    = (int*)(ws + WS_CANDI);
    float* candS    = ws + WS_CANDS;
    u16*   Xhi      = (u16*)(ws + WS_XHI);
    u16*   Ehi      = (u16*)(ws + WS_EHI);
    float* counts   = ws + WS_COUNTS;
    float* sums     = ws + WS_SUMS;
    int*   flagCnt  = (int*)(ws + WS_FLAGCNT);
    u64*   rescueBuf= (u64*)(ws + WS_RESCUE);   // aliases dead Xhi

    hipMemsetAsync((char*)d_ws + WS_ZERO_OFF_BYTES, 0, WS_ZERO_BYTES, stream);

    prep_kernel<<<(M_TOK + VOC) / 4, 256, 0, stream>>>(
        input, embed, Xhi, Ehi, esq);

    dim3 g1(M_TOK / BM, VOC / BN);
    mfma_argmin_kernel<<<g1, 256, 0, stream>>>(
        Xhi, Ehi, esq, candV, candI, candS);

    reduce_kernel<<<M_TOK / 64, 64, 0, stream>>>(
        candV, candI, candS, flagCnt, flagRows, rescueBuf);

    rescue_kernel<<<1024, 256, 0, stream>>>(
        input, embed, esq, flagCnt, flagRows, rescueBuf);

    assign_kernel<<<M_TOK / 4, 256, 0, stream>>>(
        input, embed, rescueBuf, out + OUT_Q, out + OUT_C, counts, sums);

    finalize_kernel<<<(VOC * DIM) / 256, 256, 0, stream>>>(
        cluster, embed_avg, counts, sums,
        out + OUT_NE, out + OUT_NCS, out + OUT_NEA);
}

// Round 5
// 397.990 us; speedup vs baseline: 1.4509x; 1.4509x over previous
//
#include <hip/hip_runtime.h>
#include <math.h>

// Problem constants (fixed by setup_inputs)
#define M_TOK 16384   // B*T
#define DIM   256     // D (=K)
#define VOC   8192    // V (=N)

// GEMM tiling (R2-proven 128x128 structure, BK=64 as two 32-slices)
#define BM 128
#define BN 128
#define NBLK_N (VOC / BN)   // 64
// hi-only GEMM: d2 error sigma ~0.05 (bf16 RN 2^-9, K=256). GAP_EPS = window
// bound W = 1.5 (~30 sigma). Rows with top-2 gap < W go to window-rescue:
// exact fp32 check of all codes whose APPROX d2 < approxBest + W (provably
// contains the exact argmin when 2*err <= W). Per-block top-2 makes this
// pruning sound: block excluded iff candV[blk] >= bound; deep-rescan iff
// candS[blk] < bound (rare).
#define GAP_EPS 1.5f

typedef unsigned short u16;
typedef unsigned long long u64;
typedef __attribute__((ext_vector_type(8))) __bf16 bf16x8;
typedef __attribute__((ext_vector_type(4))) float f32x4;

// ---- workspace layout (float-element offsets) ------------------------------
#define WS_ESQ      0                     // [8192]
#define WS_FLAGROWS 24576                 // [16384] int
#define WS_CANDV    40960                 // [64][16384] f32
#define WS_CANDI    1089536               // [64][16384] int
#define WS_CANDS    2138112               // [64][16384] f32
#define WS_XHI      3186688               // [16384*256] bf16 (2097152 f32 slots)
#define WS_EHI      7380992               // [8192*256] bf16 (1048576 slots)
#define WS_COUNTS   9478144               // [8192]
#define WS_SUMS     9486336               // [8192*256]
#define WS_FLAGCNT  11583488              // [16] int
// rescueBuf [16384] u64 aliases Xhi (dead after mfma_argmin; reduce writes it)
#define WS_RESCUE   WS_XHI
#define WS_ZERO_OFF_BYTES ((size_t)WS_COUNTS * 4)
#define WS_ZERO_BYTES     ((size_t)(8192 + 2097152 + 16) * 4)

// ---- out layout (float-element offsets): quantize, codes, new_embed, new_cs, new_ea
#define OUT_Q   0
#define OUT_C   4194304
#define OUT_NE  4210688
#define OUT_NCS 6307840
#define OUT_NEA 6316032

__device__ inline u16 f2bf_rn(float x) {
    unsigned u = __float_as_uint(x);
    unsigned r = u + 0x7FFFu + ((u >> 16) & 1u);   // round-to-nearest-even
    return (u16)(r >> 16);
}
__device__ inline unsigned f2key(float f) {          // order-preserving uint
    unsigned b = __float_as_uint(f);
    return (b & 0x80000000u) ? ~b : (b | 0x80000000u);
}

// ---------------------------------------------------------------------------
// prep: round X,E to bf16 (hi only); compute esq from fp32 originals.
__global__ __launch_bounds__(256) void prep_kernel(
    const float* __restrict__ X, const float* __restrict__ E,
    u16* __restrict__ Xhi, u16* __restrict__ Ehi,
    float* __restrict__ esq)
{
    int row  = blockIdx.x * 4 + (threadIdx.x >> 6);
    int lane = threadIdx.x & 63;
    bool isX = row < M_TOK;
    int r = isX ? row : row - M_TOK;
    const float* src = isX ? X + (size_t)row * DIM : E + (size_t)r * DIM;
    float4 v = ((const float4*)src)[lane];

    ushort4 h;
    h.x = f2bf_rn(v.x); h.y = f2bf_rn(v.y);
    h.z = f2bf_rn(v.z); h.w = f2bf_rn(v.w);
    u16* dh = isX ? Xhi : Ehi;
    *(ushort4*)&dh[(size_t)r * DIM + lane * 4] = h;

    if (!isX) {
        float s = v.x * v.x + v.y * v.y + v.z * v.z + v.w * v.w;
        #pragma unroll
        for (int o = 1; o < 64; o <<= 1) s += __shfl_xor(s, o, 64);
        if (lane == 0) esq[r] = s;
    }
}

// ---------------------------------------------------------------------------
// mfma_argmin (hi-only, R4-proven: ~126us): BK=64 per barrier-pair, 4 staged
// 8KB subtiles (A k0/k1, B k0/k1), 32 MFMAs per step, 4 steps.
// dot = bf16(x).bf16(e); epilogue tracks per-row top-2 of (esq[n] - 2*dot);
// rows with gap < GAP_EPS are re-solved exactly in wrescue_kernel.
// LDS staged via global_load_lds(16B) with XOR chunk swizzle (DMA forbids
// padding; swizzle keeps frag ds_read_b128 at <=2-way bank alias = free).
// Epilogue smB/I/S alias the dead tiles buffer -> LDS_Block_Size = 32768.
__global__ __launch_bounds__(256, 2) void mfma_argmin_kernel(
    const u16* __restrict__ Xhi, const u16* __restrict__ Ehi,
    const float* __restrict__ esq,
    float* __restrict__ candV, int* __restrict__ candI, float* __restrict__ candS)
{
    __shared__ __align__(16) char tiles[4 * 8192];   // A_k0, A_k1, B_k0, B_k1

    const int tid = threadIdx.x;
    const int w = tid >> 6, l = tid & 63;
    const int wy = w >> 1, wx = w & 1;
    const int m0 = blockIdx.x * BM;
    const int n0 = blockIdx.y * BN;

    f32x4 acc[4][4];
    #pragma unroll
    for (int i = 0; i < 4; ++i)
        #pragma unroll
        for (int j = 0; j < 4; ++j) acc[i][j] = (f32x4)0.0f;

    // staging: wave w stages subtile w (0=A_k0 1=A_k1 2=B_k0 3=B_k1)
    const u16* gbase = (w < 2) ? Xhi : Ehi;
    const int row0   = (w < 2) ? m0 : n0;
    const int koff   = (w & 1) * 32;                 // k-half within the 64-slice
    const int swz_c = (l & 3) ^ ((l >> 3) & 3);
    const u16* gsrc0 = gbase + (size_t)(row0 + (l >> 2)) * DIM + koff + swz_c * 8;
    char* ltile = tiles + w * 8192;

    const int frow = l & 15, fq = l >> 4;
    const int fs = ((fq ^ ((frow >> 1) & 3)) * 16);
    const char* a0P = tiles + 0 * 8192 + (wy * 64 + frow) * 64 + fs;
    const char* a1P = tiles + 1 * 8192 + (wy * 64 + frow) * 64 + fs;
    const char* b0P = tiles + 2 * 8192 + (wx * 64 + frow) * 64 + fs;
    const char* b1P = tiles + 3 * 8192 + (wx * 64 + frow) * 64 + fs;

    for (int ks = 0; ks < 4; ++ks) {
        const int k0 = ks * 64;
        __syncthreads();
        #pragma unroll
        for (int i = 0; i < 8; ++i) {
            __builtin_amdgcn_global_load_lds(
                (const __attribute__((address_space(1))) unsigned int*)(gsrc0 + (size_t)i * 16 * DIM + k0),
                (__attribute__((address_space(3))) unsigned int*)(ltile + i * 1024),
                16, 0, 0);
        }
        __syncthreads();

        bf16x8 a0[4], a1[4];
        #pragma unroll
        for (int mt = 0; mt < 4; ++mt) {
            a0[mt] = *(const bf16x8*)(a0P + mt * 1024);
            a1[mt] = *(const bf16x8*)(a1P + mt * 1024);
        }
        #pragma unroll
        for (int nt = 0; nt < 4; ++nt) {
            bf16x8 b0 = *(const bf16x8*)(b0P + nt * 1024);
            bf16x8 b1 = *(const bf16x8*)(b1P + nt * 1024);
            #pragma unroll
            for (int mt = 0; mt < 4; ++mt) {
                acc[mt][nt] = __builtin_amdgcn_mfma_f32_16x16x32_bf16(a0[mt], b0, acc[mt][nt], 0, 0, 0);
                acc[mt][nt] = __builtin_amdgcn_mfma_f32_16x16x32_bf16(a1[mt], b1, acc[mt][nt], 0, 0, 0);
            }
        }
    }

    // tiles are dead from here; re-use for the cross-wave reduce arrays
    __syncthreads();
    float* smB = (float*)tiles;            // [2][128]
    int*   smI = (int*)(tiles + 1024);     // [2][128]
    float* smS = (float*)(tiles + 2048);   // [2][128]

    // epilogue: per-row top-2 argmin of val = esq[n] - 2*dot
    float eq[4];
    #pragma unroll
    for (int nt = 0; nt < 4; ++nt) eq[nt] = esq[n0 + wx * 64 + nt * 16 + frow];

    #pragma unroll
    for (int mt = 0; mt < 4; ++mt) {
        #pragma unroll
        for (int r = 0; r < 4; ++r) {
            float b = 3.4e38f, s = 3.4e38f;
            int bi = 0;
            #pragma unroll
            for (int nt = 0; nt < 4; ++nt) {
                float v = fmaf(-2.0f, acc[mt][nt][r], eq[nt]);
                int col = n0 + wx * 64 + nt * 16 + frow;
                if (v < b) { s = b; b = v; bi = col; }
                else if (v < s) s = v;
            }
            #pragma unroll
            for (int o = 1; o < 16; o <<= 1) {
                float ob = __shfl_xor(b, o, 64);
                int   oi = __shfl_xor(bi, o, 64);
                float os = __shfl_xor(s, o, 64);
                bool take = (ob < b) || (ob == b && oi < bi);
                float keep = take ? b : ob;
                b  = take ? ob : b;
                bi = take ? oi : bi;
                s  = fminf(fminf(s, os), keep);
            }
            if (frow == 0) {
                int m_loc = wy * 64 + mt * 16 + fq * 4 + r;
                smB[wx * 128 + m_loc] = b;
                smI[wx * 128 + m_loc] = bi;
                smS[wx * 128 + m_loc] = s;
            }
        }
    }
    __syncthreads();
    if (tid < 128) {
        float b0 = smB[tid],       b1 = smB[128 + tid];
        int   i0 = smI[tid],       i1 = smI[128 + tid];
        float s0 = smS[tid],       s1 = smS[128 + tid];
        bool take = (b1 < b0);                 // tie -> wave 0 (lower cols)
        float b = take ? b1 : b0;
        int  bi = take ? i1 : i0;
        float s = fminf(fminf(s0, s1), take ? b0 : b1);
        size_t e = (size_t)blockIdx.y * M_TOK + (m0 + tid);
        candV[e] = b; candI[e] = bi; candS[e] = s;
    }
}

// ---------------------------------------------------------------------------
// reduce: fold 64 n-block candidates per row. Batched-8 independent candV
// loads; candS/candI read lazily only for the winning block (true global
// second = min(2nd-min over candV, candS[e*])). Packs (key|idx) u64 into
// rescueBuf; flagged rows get ~0 sentinel, overwritten by wrescue.
__global__ __launch_bounds__(64) void reduce_kernel(
    const float* __restrict__ candV, const int* __restrict__ candI,
    const float* __restrict__ candS,
    int* __restrict__ flagCnt, int* __restrict__ flagRows,
    u64* __restrict__ rescueBuf)
{
    int row = blockIdx.x * 64 + threadIdx.x;
    float best = 3.4e38f, second = 3.4e38f;
    int ebest = 0;
    #pragma unroll
    for (int e0 = 0; e0 < NBLK_N; e0 += 8) {
        float v[8];
        #pragma unroll
        for (int j = 0; j < 8; ++j) v[j] = candV[(size_t)(e0 + j) * M_TOK + row];
        #pragma unroll
        for (int j = 0; j < 8; ++j) {
            if (v[j] < best) { second = best; best = v[j]; ebest = e0 + j; }
            else second = fminf(second, v[j]);
        }
    }
    int bi = candI[(size_t)ebest * M_TOK + row];
    second = fminf(second, candS[(size_t)ebest * M_TOK + row]);
    u64 pk = ((u64)f2key(best) << 32) | (unsigned)bi;
    if (second - best < GAP_EPS) {
        pk = ~0ull;
        int k = atomicAdd(flagCnt, 1);
        flagRows[k] = row;
    }
    rescueBuf[row] = pk;
}

// ---------------------------------------------------------------------------
// wrescue: exact fp32 argmin for flagged rows via candidate-window pruning.
// One wave per flagged row. Soundness: |approx-exact| <= eps per code =>
// exact argmin has approx d2 < approxBest + 2*eps <= approxBest + W.
// Block e is excluded iff candV[e] >= bound (candV is the block MIN);
// blocks with candV < bound contribute candI[e]; blocks with candS < bound
// (rare, ~1%) are rescanned fully (codes beyond top-2 are unbounded there).
// Typical cost/row: ~2-4 exact evals (1KB E row + 512 FLOP + shfl reduce).
// No atomics: the wave owns the row and overwrites reduce's sentinel.
__global__ __launch_bounds__(256) void wrescue_kernel(
    const float* __restrict__ X, const float* __restrict__ E,
    const float* __restrict__ esq,
    const float* __restrict__ candV, const int* __restrict__ candI,
    const float* __restrict__ candS,
    const int* __restrict__ flagCnt, const int* __restrict__ flagRows,
    u64* __restrict__ rescueBuf)
{
    const int nflag = flagCnt[0];
    const int lane = threadIdx.x & 63;
    const int gw = blockIdx.x * 4 + (threadIdx.x >> 6);
    const int nwaves = gridDim.x * 4;

    for (int f = gw; f < nflag; f += nwaves) {
        const int row = flagRows[f];
        // lane e holds block-e candidates (NBLK_N == 64 == wave size)
        float bv = candV[(size_t)lane * M_TOK + row];
        float bs = candS[(size_t)lane * M_TOK + row];
        int   bi = candI[(size_t)lane * M_TOK + row];

        float g = bv;
        #pragma unroll
        for (int o = 1; o < 64; o <<= 1) g = fminf(g, __shfl_xor(g, o, 64));
        const float bound = g + GAP_EPS;

        float4 x4 = *(const float4*)&X[(size_t)row * DIM + lane * 4];

        float bestV = 3.4e38f;
        int   bestI = 0x7FFFFFFF;

        // block bests inside the window
        u64 mask = __ballot(bv < bound);
        while (mask) {
            int src = __ffsll((unsigned long long)mask) - 1;
            mask &= mask - 1;
            int c = __shfl(bi, src, 64);
            float4 e4 = *(const float4*)&E[(size_t)c * DIM + lane * 4];
            float d = x4.x * e4.x + x4.y * e4.y + x4.z * e4.z + x4.w * e4.w;
            #pragma unroll
            for (int o = 1; o < 64; o <<= 1) d += __shfl_xor(d, o, 64);
            float v = fmaf(-2.0f, d, esq[c]);
            if (v < bestV || (v == bestV && c < bestI)) { bestV = v; bestI = c; }
        }
        // deep blocks: second-best also inside window -> rescan 128 codes
        u64 dmask = __ballot(bs < bound);
        while (dmask) {
            int e = __ffsll((unsigned long long)dmask) - 1;
            dmask &= dmask - 1;
            for (int c = e * BN; c < e * BN + BN; ++c) {
                float4 e4 = *(const float4*)&E[(size_t)c * DIM + lane * 4];
                float d = x4.x * e4.x + x4.y * e4.y + x4.z * e4.z + x4.w * e4.w;
                #pragma unroll
                for (int o = 1; o < 64; o <<= 1) d += __shfl_xor(d, o, 64);
                float v = fmaf(-2.0f, d, esq[c]);
                if (v < bestV || (v == bestV && c < bestI)) { bestV = v; bestI = c; }
            }
        }
        if (lane == 0)
            rescueBuf[row] = ((u64)f2key(bestV) << 32) | (unsigned)bestI;
    }
}

// ---------------------------------------------------------------------------
// assign: unpack code, write codes + quantize (STE), scatter counts/sums.
__global__ __launch_bounds__(256) void assign_kernel(
    const float* __restrict__ X, const float* __restrict__ E,
    const u64* __restrict__ rescueBuf,
    float* __restrict__ out_q, float* __restrict__ out_codes,
    float* __restrict__ counts, float* __restrict__ sums)
{
    int t = blockIdx.x * 4 + (threadIdx.x >> 6);
    int lane = threadIdx.x & 63;
    int code = (int)(unsigned)(rescueBuf[t] & 0xFFFFFFFFull);
    if (lane == 0) {
        out_codes[t] = (float)code;
        atomicAdd(&counts[code], 1.0f);
    }
    float4 x = *(const float4*)&X[(size_t)t * DIM + lane * 4];
    float4 e = *(const float4*)&E[(size_t)code * DIM + lane * 4];
    float4 q;
    q.x = x.x + (e.x - x.x);
    q.y = x.y + (e.y - x.y);
    q.z = x.z + (e.z - x.z);
    q.w = x.w + (e.w - x.w);
    *(float4*)&out_q[(size_t)t * DIM + lane * 4] = q;
    float* s = &sums[(size_t)code * DIM + lane * 4];
    atomicAdd(s + 0, x.x);
    atomicAdd(s + 1, x.y);
    atomicAdd(s + 2, x.z);
    atomicAdd(s + 3, x.w);
}

// ---------------------------------------------------------------------------
__global__ __launch_bounds__(256) void finalize_kernel(
    const float* __restrict__ cs, const float* __restrict__ ea,
    const float* __restrict__ counts, const float* __restrict__ sums,
    float* __restrict__ out_embed, float* __restrict__ out_cs,
    float* __restrict__ out_ea)
{
    int vd = blockIdx.x * 256 + threadIdx.x;
    int v = vd >> 8, d = vd & 255;
    float cnt = counts[v];
    float ncs = cs[v] * 0.99f + cnt * 0.01f;
    float cb  = sums[vd] * (1.0f / 2048.0f);
    float nea = ea[vd] * 0.99f + cb * 0.01f;
    out_ea[vd] = nea;
    out_embed[vd] = nea / (ncs + 1e-5f);
    if (d == 0) out_cs[v] = ncs;
}

// ---------------------------------------------------------------------------
extern "C" void kernel_launch(void* const* d_in, const int* in_sizes, int n_in,
                              void* d_out, int out_size, void* d_ws, size_t ws_size,
                              hipStream_t stream)
{
    const float* input     = (const float*)d_in[0];
    const float* embed     = (const float*)d_in[1];
    const float* cluster   = (const float*)d_in[2];
    const float* embed_avg = (const float*)d_in[3];

    float* out = (float*)d_out;
    float* ws  = (float*)d_ws;

    float* esq      = ws + WS_ESQ;
    int*   flagRows = (int*)(ws + WS_FLAGROWS);
    float* candV    = ws + WS_CANDV;
    int*   candI    = (int*)(ws + WS_CANDI);
    float* candS    = ws + WS_CANDS;
    u16*   Xhi      = (u16*)(ws + WS_XHI);
    u16*   Ehi      = (u16*)(ws + WS_EHI);
    float* counts   = ws + WS_COUNTS;
    float* sums     = ws + WS_SUMS;
    int*   flagCnt  = (int*)(ws + WS_FLAGCNT);
    u64*   rescueBuf= (u64*)(ws + WS_RESCUE);   // aliases dead Xhi

    hipMemsetAsync((char*)d_ws + WS_ZERO_OFF_BYTES, 0, WS_ZERO_BYTES, stream);

    prep_kernel<<<(M_TOK + VOC) / 4, 256, 0, stream>>>(
        input, embed, Xhi, Ehi, esq);

    dim3 g1(M_TOK / BM, VOC / BN);
    mfma_argmin_kernel<<<g1, 256, 0, stream>>>(
        Xhi, Ehi, esq, candV, candI, candS);

    reduce_kernel<<<M_TOK / 64, 64, 0, stream>>>(
        candV, candI, candS, flagCnt, flagRows, rescueBuf);

    wrescue_kernel<<<512, 256, 0, stream>>>(
        input, embed, esq, candV, candI, candS, flagCnt, flagRows, rescueBuf);

    assign_kernel<<<M_TOK / 4, 256, 0, stream>>>(
        input, embed, rescueBuf, out + OUT_Q, out + OUT_C, counts, sums);

    finalize_kernel<<<(VOC * DIM) / 256, 256, 0, stream>>>(
        cluster, embed_avg, counts, sums,
        out + OUT_NE, out + OUT_NCS, out + OUT_NEA);
}

// Round 6
// 334.210 us; speedup vs baseline: 1.7277x; 1.1908x over previous
//
#include <hip/hip_runtime.h>
#include <math.h>

// Problem constants (fixed by setup_inputs)
#define M_TOK 16384   // B*T
#define DIM   256     // D (=K)
#define VOC   8192    // V (=N)

// GEMM tiling (R2-proven 128x128 structure, BK=64 as two 32-slices)
#define BM 128
#define BN 128
#define NBLK_N (VOC / BN)   // 64
// hi-only GEMM: d2 error sigma ~0.05 (bf16 RN 2^-9, K=256). GAP_EPS = window
// bound W = 1.5 (~30 sigma). Rows with top-2 gap < W get window-rescue:
// exact fp32 check of all codes whose APPROX d2 < approxBest + W (provably
// contains the exact argmin when 2*err <= W). Per-block top-2 makes the
// pruning sound: block fully excluded iff candV[blk] >= bound; cheap-eval
// candI[blk] iff candV[blk] < bound; full 128-code rescan iff candS[blk]
// < bound (codes beyond top-2 are unbounded there; rare).
#define GAP_EPS 1.5f

typedef unsigned short u16;
typedef unsigned long long u64;
typedef __attribute__((ext_vector_type(8))) __bf16 bf16x8;
typedef __attribute__((ext_vector_type(4))) float f32x4;

// ---- workspace layout (float-element offsets) ------------------------------
#define WS_ESQ      0                     // [8192]
#define WS_CANDV    40960                 // [64][16384] f32
#define WS_CANDI    1089536               // [64][16384] int
#define WS_CANDS    2138112               // [64][16384] f32
#define WS_XHI      3186688               // [16384*256] bf16 (2097152 f32 slots)
#define WS_EHI      7380992               // [8192*256] bf16 (1048576 slots)
#define WS_COUNTS   9478144               // [8192]
#define WS_SUMS     9486336               // [8192*256]
#define WS_ZERO_OFF_BYTES ((size_t)WS_COUNTS * 4)
#define WS_ZERO_BYTES     ((size_t)(8192 + 2097152 + 16) * 4)

// ---- out layout (float-element offsets): quantize, codes, new_embed, new_cs, new_ea
#define OUT_Q   0
#define OUT_C   4194304
#define OUT_NE  4210688
#define OUT_NCS 6307840
#define OUT_NEA 6316032

__device__ inline u16 f2bf_rn(float x) {
    unsigned u = __float_as_uint(x);
    unsigned r = u + 0x7FFFu + ((u >> 16) & 1u);   // round-to-nearest-even
    return (u16)(r >> 16);
}
__device__ inline unsigned f2key(float f) {          // order-preserving uint
    unsigned b = __float_as_uint(f);
    return (b & 0x80000000u) ? ~b : (b | 0x80000000u);
}
__device__ inline float key2f(unsigned k) {          // inverse of f2key
    unsigned b = (k & 0x80000000u) ? (k ^ 0x80000000u) : ~k;
    return __uint_as_float(b);
}

// ---------------------------------------------------------------------------
// prep: round X,E to bf16 (hi only); compute esq from fp32 originals.
__global__ __launch_bounds__(256) void prep_kernel(
    const float* __restrict__ X, const float* __restrict__ E,
    u16* __restrict__ Xhi, u16* __restrict__ Ehi,
    float* __restrict__ esq)
{
    int row  = blockIdx.x * 4 + (threadIdx.x >> 6);
    int lane = threadIdx.x & 63;
    bool isX = row < M_TOK;
    int r = isX ? row : row - M_TOK;
    const float* src = isX ? X + (size_t)row * DIM : E + (size_t)r * DIM;
    float4 v = ((const float4*)src)[lane];

    ushort4 h;
    h.x = f2bf_rn(v.x); h.y = f2bf_rn(v.y);
    h.z = f2bf_rn(v.z); h.w = f2bf_rn(v.w);
    u16* dh = isX ? Xhi : Ehi;
    *(ushort4*)&dh[(size_t)r * DIM + lane * 4] = h;

    if (!isX) {
        float s = v.x * v.x + v.y * v.y + v.z * v.z + v.w * v.w;
        #pragma unroll
        for (int o = 1; o < 64; o <<= 1) s += __shfl_xor(s, o, 64);
        if (lane == 0) esq[r] = s;
    }
}

// ---------------------------------------------------------------------------
// mfma_argmin (hi-only, R5-proven: 148.7us): BK=64 per barrier-pair, 4 staged
// 8KB subtiles (A k0/k1, B k0/k1), 32 MFMAs per step, 4 steps.
// dot = bf16(x).bf16(e); epilogue tracks per-row top-2 of (esq[n] - 2*dot);
// rows with gap < GAP_EPS are re-solved exactly in post_kernel.
// LDS staged via global_load_lds(16B) with XOR chunk swizzle (DMA forbids
// padding; swizzle keeps frag ds_read_b128 at <=2-way bank alias = free).
// Epilogue smB/I/S alias the dead tiles buffer -> LDS_Block_Size = 32768.
__global__ __launch_bounds__(256, 2) void mfma_argmin_kernel(
    const u16* __restrict__ Xhi, const u16* __restrict__ Ehi,
    const float* __restrict__ esq,
    float* __restrict__ candV, int* __restrict__ candI, float* __restrict__ candS)
{
    __shared__ __align__(16) char tiles[4 * 8192];   // A_k0, A_k1, B_k0, B_k1

    const int tid = threadIdx.x;
    const int w = tid >> 6, l = tid & 63;
    const int wy = w >> 1, wx = w & 1;
    const int m0 = blockIdx.x * BM;
    const int n0 = blockIdx.y * BN;

    f32x4 acc[4][4];
    #pragma unroll
    for (int i = 0; i < 4; ++i)
        #pragma unroll
        for (int j = 0; j < 4; ++j) acc[i][j] = (f32x4)0.0f;

    // staging: wave w stages subtile w (0=A_k0 1=A_k1 2=B_k0 3=B_k1)
    const u16* gbase = (w < 2) ? Xhi : Ehi;
    const int row0   = (w < 2) ? m0 : n0;
    const int koff   = (w & 1) * 32;                 // k-half within the 64-slice
    const int swz_c = (l & 3) ^ ((l >> 3) & 3);
    const u16* gsrc0 = gbase + (size_t)(row0 + (l >> 2)) * DIM + koff + swz_c * 8;
    char* ltile = tiles + w * 8192;

    const int frow = l & 15, fq = l >> 4;
    const int fs = ((fq ^ ((frow >> 1) & 3)) * 16);
    const char* a0P = tiles + 0 * 8192 + (wy * 64 + frow) * 64 + fs;
    const char* a1P = tiles + 1 * 8192 + (wy * 64 + frow) * 64 + fs;
    const char* b0P = tiles + 2 * 8192 + (wx * 64 + frow) * 64 + fs;
    const char* b1P = tiles + 3 * 8192 + (wx * 64 + frow) * 64 + fs;

    for (int ks = 0; ks < 4; ++ks) {
        const int k0 = ks * 64;
        __syncthreads();
        #pragma unroll
        for (int i = 0; i < 8; ++i) {
            __builtin_amdgcn_global_load_lds(
                (const __attribute__((address_space(1))) unsigned int*)(gsrc0 + (size_t)i * 16 * DIM + k0),
                (__attribute__((address_space(3))) unsigned int*)(ltile + i * 1024),
                16, 0, 0);
        }
        __syncthreads();

        bf16x8 a0[4], a1[4];
        #pragma unroll
        for (int mt = 0; mt < 4; ++mt) {
            a0[mt] = *(const bf16x8*)(a0P + mt * 1024);
            a1[mt] = *(const bf16x8*)(a1P + mt * 1024);
        }
        #pragma unroll
        for (int nt = 0; nt < 4; ++nt) {
            bf16x8 b0 = *(const bf16x8*)(b0P + nt * 1024);
            bf16x8 b1 = *(const bf16x8*)(b1P + nt * 1024);
            #pragma unroll
            for (int mt = 0; mt < 4; ++mt) {
                acc[mt][nt] = __builtin_amdgcn_mfma_f32_16x16x32_bf16(a0[mt], b0, acc[mt][nt], 0, 0, 0);
                acc[mt][nt] = __builtin_amdgcn_mfma_f32_16x16x32_bf16(a1[mt], b1, acc[mt][nt], 0, 0, 0);
            }
        }
    }

    // tiles are dead from here; re-use for the cross-wave reduce arrays
    __syncthreads();
    float* smB = (float*)tiles;            // [2][128]
    int*   smI = (int*)(tiles + 1024);     // [2][128]
    float* smS = (float*)(tiles + 2048);   // [2][128]

    // epilogue: per-row top-2 argmin of val = esq[n] - 2*dot
    float eq[4];
    #pragma unroll
    for (int nt = 0; nt < 4; ++nt) eq[nt] = esq[n0 + wx * 64 + nt * 16 + frow];

    #pragma unroll
    for (int mt = 0; mt < 4; ++mt) {
        #pragma unroll
        for (int r = 0; r < 4; ++r) {
            float b = 3.4e38f, s = 3.4e38f;
            int bi = 0;
            #pragma unroll
            for (int nt = 0; nt < 4; ++nt) {
                float v = fmaf(-2.0f, acc[mt][nt][r], eq[nt]);
                int col = n0 + wx * 64 + nt * 16 + frow;
                if (v < b) { s = b; b = v; bi = col; }
                else if (v < s) s = v;
            }
            #pragma unroll
            for (int o = 1; o < 16; o <<= 1) {
                float ob = __shfl_xor(b, o, 64);
                int   oi = __shfl_xor(bi, o, 64);
                float os = __shfl_xor(s, o, 64);
                bool take = (ob < b) || (ob == b && oi < bi);
                float keep = take ? b : ob;
                b  = take ? ob : b;
                bi = take ? oi : bi;
                s  = fminf(fminf(s, os), keep);
            }
            if (frow == 0) {
                int m_loc = wy * 64 + mt * 16 + fq * 4 + r;
                smB[wx * 128 + m_loc] = b;
                smI[wx * 128 + m_loc] = bi;
                smS[wx * 128 + m_loc] = s;
            }
        }
    }
    __syncthreads();
    if (tid < 128) {
        float b0 = smB[tid],       b1 = smB[128 + tid];
        int   i0 = smI[tid],       i1 = smI[128 + tid];
        float s0 = smS[tid],       s1 = smS[128 + tid];
        bool take = (b1 < b0);                 // tie -> wave 0 (lower cols)
        float b = take ? b1 : b0;
        int  bi = take ? i1 : i0;
        float s = fminf(fminf(s0, s1), take ? b0 : b1);
        size_t e = (size_t)blockIdx.y * M_TOK + (m0 + tid);
        candV[e] = b; candI[e] = bi; candS[e] = s;
    }
}

// ---------------------------------------------------------------------------
// post: fused reduce + window-rescue + assign. One wave per row (4 rows/wave).
// Lane e holds block-e candidates (NBLK_N == 64 == wave size); packed-u64
// min butterfly gives best with lowest-index tie-break (== reference argmin
// semantics: earlier block => smaller index). second = min over lanes of
// (bestlane ? candS : candV) == min(2nd-min over candV, candS[best]) exactly
// as the old reduce computed. Flagged rows (gap < W) window-rescue inline:
// candidates are already in registers; deep blocks (candS < bound) rescan
// 128 codes batched 4-wide for ILP across the shuffle-reduce chains. No
// atomics/flag indirection: the wave owns its row. X row is loaded once and
// reused for both the exact dot and the STE quantize write.
__global__ __launch_bounds__(256) void post_kernel(
    const float* __restrict__ X, const float* __restrict__ E,
    const float* __restrict__ esq,
    const float* __restrict__ candV, const int* __restrict__ candI,
    const float* __restrict__ candS,
    float* __restrict__ out_q, float* __restrict__ out_codes,
    float* __restrict__ counts, float* __restrict__ sums)
{
    const int lane = threadIdx.x & 63;
    const int wv   = threadIdx.x >> 6;
    const int row0 = blockIdx.x * 16 + wv * 4;   // 4 consecutive rows per wave
                                                 // (cand line reuse across rr)
    for (int rr = 0; rr < 4; ++rr) {
        const int row = row0 + rr;
        float bv = candV[(size_t)lane * M_TOK + row];
        float bs = candS[(size_t)lane * M_TOK + row];
        int   bi = candI[(size_t)lane * M_TOK + row];

        u64 pk = ((u64)f2key(bv) << 32) | (unsigned)bi;
        u64 m = pk;
        #pragma unroll
        for (int o = 1; o < 64; o <<= 1) {
            u64 other = __shfl_xor(m, o, 64);
            m = (other < m) ? other : m;
        }
        float best = key2f((unsigned)(m >> 32));
        int   code = (int)(unsigned)(m & 0xFFFFFFFFull);

        float sec = (pk == m) ? bs : bv;     // bestlane unique (pk has index)
        #pragma unroll
        for (int o = 1; o < 64; o <<= 1) sec = fminf(sec, __shfl_xor(sec, o, 64));

        const float4 x4 = ((const float4*)&X[(size_t)row * DIM])[lane];

        if (sec - best < GAP_EPS) {          // wave-uniform branch
            const float bound = best + GAP_EPS;
            float bestV = 3.4e38f;
            int   bestI = 0x7FFFFFFF;
            // cheap: exact-eval block bests inside the window (incl. code)
            u64 mask = __ballot(bv < bound);
            while (mask) {
                int src = __ffsll((unsigned long long)mask) - 1;
                mask &= mask - 1;
                int c = __shfl(bi, src, 64);
                float4 e4 = ((const float4*)&E[(size_t)c * DIM])[lane];
                float d = x4.x * e4.x + x4.y * e4.y + x4.z * e4.z + x4.w * e4.w;
                #pragma unroll
                for (int o = 1; o < 64; o <<= 1) d += __shfl_xor(d, o, 64);
                float v = fmaf(-2.0f, d, esq[c]);
                if (v < bestV || (v == bestV && c < bestI)) { bestV = v; bestI = c; }
            }
            // deep: block second also in window -> full rescan, 4-wide ILP
            u64 dmask = __ballot(bs < bound);
            while (dmask) {
                int e = __ffsll((unsigned long long)dmask) - 1;
                dmask &= dmask - 1;
                const int c0 = e * BN;
                for (int j = 0; j < BN; j += 4) {
                    float4 e0 = ((const float4*)&E[(size_t)(c0 + j + 0) * DIM])[lane];
                    float4 e1 = ((const float4*)&E[(size_t)(c0 + j + 1) * DIM])[lane];
                    float4 e2 = ((const float4*)&E[(size_t)(c0 + j + 2) * DIM])[lane];
                    float4 e3 = ((const float4*)&E[(size_t)(c0 + j + 3) * DIM])[lane];
                    float d0 = x4.x * e0.x + x4.y * e0.y + x4.z * e0.z + x4.w * e0.w;
                    float d1 = x4.x * e1.x + x4.y * e1.y + x4.z * e1.z + x4.w * e1.w;
                    float d2 = x4.x * e2.x + x4.y * e2.y + x4.z * e2.z + x4.w * e2.w;
                    float d3 = x4.x * e3.x + x4.y * e3.y + x4.z * e3.z + x4.w * e3.w;
                    #pragma unroll
                    for (int o = 1; o < 64; o <<= 1) {
                        d0 += __shfl_xor(d0, o, 64);
                        d1 += __shfl_xor(d1, o, 64);
                        d2 += __shfl_xor(d2, o, 64);
                        d3 += __shfl_xor(d3, o, 64);
                    }
                    float v0 = fmaf(-2.0f, d0, esq[c0 + j + 0]);
                    float v1 = fmaf(-2.0f, d1, esq[c0 + j + 1]);
                    float v2 = fmaf(-2.0f, d2, esq[c0 + j + 2]);
                    float v3 = fmaf(-2.0f, d3, esq[c0 + j + 3]);
                    if (v0 < bestV || (v0 == bestV && c0 + j + 0 < bestI)) { bestV = v0; bestI = c0 + j + 0; }
                    if (v1 < bestV || (v1 == bestV && c0 + j + 1 < bestI)) { bestV = v1; bestI = c0 + j + 1; }
                    if (v2 < bestV || (v2 == bestV && c0 + j + 2 < bestI)) { bestV = v2; bestI = c0 + j + 2; }
                    if (v3 < bestV || (v3 == bestV && c0 + j + 3 < bestI)) { bestV = v3; bestI = c0 + j + 3; }
                }
            }
            code = bestI;
        }

        // assign: codes, STE quantize, EMA scatter
        if (lane == 0) {
            out_codes[row] = (float)code;
            atomicAdd(&counts[code], 1.0f);
        }
        float4 e4 = ((const float4*)&E[(size_t)code * DIM])[lane];
        float4 q;
        q.x = x4.x + (e4.x - x4.x);
        q.y = x4.y + (e4.y - x4.y);
        q.z = x4.z + (e4.z - x4.z);
        q.w = x4.w + (e4.w - x4.w);
        ((float4*)&out_q[(size_t)row * DIM])[lane] = q;
        float* s = &sums[(size_t)code * DIM + lane * 4];
        atomicAdd(s + 0, x4.x);
        atomicAdd(s + 1, x4.y);
        atomicAdd(s + 2, x4.z);
        atomicAdd(s + 3, x4.w);
    }
}

// ---------------------------------------------------------------------------
__global__ __launch_bounds__(256) void finalize_kernel(
    const float* __restrict__ cs, const float* __restrict__ ea,
    const float* __restrict__ counts, const float* __restrict__ sums,
    float* __restrict__ out_embed, float* __restrict__ out_cs,
    float* __restrict__ out_ea)
{
    int vd = blockIdx.x * 256 + threadIdx.x;
    int v = vd >> 8, d = vd & 255;
    float cnt = counts[v];
    float ncs = cs[v] * 0.99f + cnt * 0.01f;
    float cb  = sums[vd] * (1.0f / 2048.0f);
    float nea = ea[vd] * 0.99f + cb * 0.01f;
    out_ea[vd] = nea;
    out_embed[vd] = nea / (ncs + 1e-5f);
    if (d == 0) out_cs[v] = ncs;
}

// ---------------------------------------------------------------------------
extern "C" void kernel_launch(void* const* d_in, const int* in_sizes, int n_in,
                              void* d_out, int out_size, void* d_ws, size_t ws_size,
                              hipStream_t stream)
{
    const float* input     = (const float*)d_in[0];
    const float* embed     = (const float*)d_in[1];
    const float* cluster   = (const float*)d_in[2];
    const float* embed_avg = (const float*)d_in[3];

    float* out = (float*)d_out;
    float* ws  = (float*)d_ws;

    float* esq      = ws + WS_ESQ;
    float* candV    = ws + WS_CANDV;
    int*   candI    = (int*)(ws + WS_CANDI);
    float* candS    = ws + WS_CANDS;
    u16*   Xhi      = (u16*)(ws + WS_XHI);
    u16*   Ehi      = (u16*)(ws + WS_EHI);
    float* counts   = ws + WS_COUNTS;
    float* sums     = ws + WS_SUMS;

    hipMemsetAsync((char*)d_ws + WS_ZERO_OFF_BYTES, 0, WS_ZERO_BYTES, stream);

    prep_kernel<<<(M_TOK + VOC) / 4, 256, 0, stream>>>(
        input, embed, Xhi, Ehi, esq);

    dim3 g1(M_TOK / BM, VOC / BN);
    mfma_argmin_kernel<<<g1, 256, 0, stream>>>(
        Xhi, Ehi, esq, candV, candI, candS);

    post_kernel<<<M_TOK / 16, 256, 0, stream>>>(
        input, embed, esq, candV, candI, candS,
        out + OUT_Q, out + OUT_C, counts, sums);

    finalize_kernel<<<(VOC * DIM) / 256, 256, 0, stream>>>(
        cluster, embed_avg, counts, sums,
        out + OUT_NE, out + OUT_NCS, out + OUT_NEA);
}

// Round 7
// 301.867 us; speedup vs baseline: 1.9129x; 1.1071x over previous
//
#include <hip/hip_runtime.h>
#include <math.h>

// Problem constants (fixed by setup_inputs)
#define M_TOK 16384   // B*T
#define DIM   256     // D (=K)
#define VOC   8192    // V (=N)

// GEMM tiling (R2-proven 128x128 structure, BK=64 as two 32-slices)
#define BM 128
#define BN 128
#define NBLK_N (VOC / BN)   // 64
// hi-only GEMM: d2 error sigma ~0.05 (bf16 RN 2^-9, K=256). GAP_EPS = window
// bound W = 1.5 (~30 sigma). Rows with top-2 gap < W get window-rescue:
// exact fp32 check of all codes whose APPROX d2 < approxBest + W (provably
// contains the exact argmin when 2*err <= W). Per-block top-2 makes the
// pruning sound: block fully excluded iff candV[blk] >= bound; cheap-eval
// candI[blk] iff candV[blk] < bound; full 128-code rescan iff candS[blk]
// < bound (codes beyond top-2 are unbounded there; rare).
#define GAP_EPS 1.5f

typedef unsigned short u16;
typedef unsigned long long u64;
typedef __attribute__((ext_vector_type(8))) __bf16 bf16x8;
typedef __attribute__((ext_vector_type(4))) float f32x4;

// ---- workspace layout (float-element offsets) ------------------------------
#define WS_ESQ      0                     // [8192]
#define WS_CANDV    40960                 // [16384][64] f32  (row-major now)
#define WS_CANDI    1089536               // [16384][64] int
#define WS_CANDS    2138112               // [16384][64] f32
#define WS_XHI      3186688               // [16384*256] bf16 (2097152 f32 slots)
#define WS_EHI      7380992               // [8192*256] bf16 (1048576 slots)
#define WS_COUNTS   9478144               // [8192]
#define WS_SUMS     9486336               // [8192*256]
#define WS_ZERO_OFF_BYTES ((size_t)WS_COUNTS * 4)
#define WS_ZERO_BYTES     ((size_t)(8192 + 2097152 + 16) * 4)

// ---- out layout (float-element offsets): quantize, codes, new_embed, new_cs, new_ea
#define OUT_Q   0
#define OUT_C   4194304
#define OUT_NE  4210688
#define OUT_NCS 6307840
#define OUT_NEA 6316032

__device__ inline u16 f2bf_rn(float x) {
    unsigned u = __float_as_uint(x);
    unsigned r = u + 0x7FFFu + ((u >> 16) & 1u);   // round-to-nearest-even
    return (u16)(r >> 16);
}
__device__ inline unsigned f2key(float f) {          // order-preserving uint
    unsigned b = __float_as_uint(f);
    return (b & 0x80000000u) ? ~b : (b | 0x80000000u);
}
__device__ inline float key2f(unsigned k) {          // inverse of f2key
    unsigned b = (k & 0x80000000u) ? (k ^ 0x80000000u) : ~k;
    return __uint_as_float(b);
}

// ---------------------------------------------------------------------------
// prep: round X,E to bf16 (hi only); compute esq from fp32 originals.
__global__ __launch_bounds__(256) void prep_kernel(
    const float* __restrict__ X, const float* __restrict__ E,
    u16* __restrict__ Xhi, u16* __restrict__ Ehi,
    float* __restrict__ esq)
{
    int row  = blockIdx.x * 4 + (threadIdx.x >> 6);
    int lane = threadIdx.x & 63;
    bool isX = row < M_TOK;
    int r = isX ? row : row - M_TOK;
    const float* src = isX ? X + (size_t)row * DIM : E + (size_t)r * DIM;
    float4 v = ((const float4*)src)[lane];

    ushort4 h;
    h.x = f2bf_rn(v.x); h.y = f2bf_rn(v.y);
    h.z = f2bf_rn(v.z); h.w = f2bf_rn(v.w);
    u16* dh = isX ? Xhi : Ehi;
    *(ushort4*)&dh[(size_t)r * DIM + lane * 4] = h;

    if (!isX) {
        float s = v.x * v.x + v.y * v.y + v.z * v.z + v.w * v.w;
        #pragma unroll
        for (int o = 1; o < 64; o <<= 1) s += __shfl_xor(s, o, 64);
        if (lane == 0) esq[r] = s;
    }
}

// ---------------------------------------------------------------------------
// mfma_argmin (hi-only, R5-proven loop; SWAPPED-OPERAND epilogue):
// mfma(B_frag, A_frag) gives D[code][token] (both frags share the same lane
// layout, so the swap is free). Per-token top-2 over codes is then a pure
// in-register scan of 16 values (4 nt x 4 r, monotone code order => lowest-
// index tie-break) + a 2-step butterfly over the fq lane-quads (o=16,32) —
// 24 bpermutes vs 192 in the old col-major epilogue (~40% of kernel time).
// Main loop: BK=64 per barrier-pair, 4 staged 8KB subtiles, 32 MFMAs/step.
// LDS staged via global_load_lds(16B) with XOR chunk swizzle (DMA forbids
// padding; swizzle keeps frag ds_read_b128 at <=2-way bank alias = free).
// candV/I/S written [row][block] so post's reads are coalesced 256B loads.
__global__ __launch_bounds__(256, 2) void mfma_argmin_kernel(
    const u16* __restrict__ Xhi, const u16* __restrict__ Ehi,
    const float* __restrict__ esq,
    float* __restrict__ candV, int* __restrict__ candI, float* __restrict__ candS)
{
    __shared__ __align__(16) char tiles[4 * 8192];   // A_k0, A_k1, B_k0, B_k1

    const int tid = threadIdx.x;
    const int w = tid >> 6, l = tid & 63;
    const int wy = w >> 1, wx = w & 1;
    const int m0 = blockIdx.x * BM;
    const int n0 = blockIdx.y * BN;

    f32x4 acc[4][4];
    #pragma unroll
    for (int i = 0; i < 4; ++i)
        #pragma unroll
        for (int j = 0; j < 4; ++j) acc[i][j] = (f32x4)0.0f;

    // staging: wave w stages subtile w (0=A_k0 1=A_k1 2=B_k0 3=B_k1)
    const u16* gbase = (w < 2) ? Xhi : Ehi;
    const int row0   = (w < 2) ? m0 : n0;
    const int koff   = (w & 1) * 32;                 // k-half within the 64-slice
    const int swz_c = (l & 3) ^ ((l >> 3) & 3);
    const u16* gsrc0 = gbase + (size_t)(row0 + (l >> 2)) * DIM + koff + swz_c * 8;
    char* ltile = tiles + w * 8192;

    const int frow = l & 15, fq = l >> 4;
    const int fs = ((fq ^ ((frow >> 1) & 3)) * 16);
    const char* a0P = tiles + 0 * 8192 + (wy * 64 + frow) * 64 + fs;
    const char* a1P = tiles + 1 * 8192 + (wy * 64 + frow) * 64 + fs;
    const char* b0P = tiles + 2 * 8192 + (wx * 64 + frow) * 64 + fs;
    const char* b1P = tiles + 3 * 8192 + (wx * 64 + frow) * 64 + fs;

    for (int ks = 0; ks < 4; ++ks) {
        const int k0 = ks * 64;
        __syncthreads();
        #pragma unroll
        for (int i = 0; i < 8; ++i) {
            __builtin_amdgcn_global_load_lds(
                (const __attribute__((address_space(1))) unsigned int*)(gsrc0 + (size_t)i * 16 * DIM + k0),
                (__attribute__((address_space(3))) unsigned int*)(ltile + i * 1024),
                16, 0, 0);
        }
        __syncthreads();

        bf16x8 a0[4], a1[4];
        #pragma unroll
        for (int mt = 0; mt < 4; ++mt) {
            a0[mt] = *(const bf16x8*)(a0P + mt * 1024);
            a1[mt] = *(const bf16x8*)(a1P + mt * 1024);
        }
        #pragma unroll
        for (int nt = 0; nt < 4; ++nt) {
            bf16x8 b0 = *(const bf16x8*)(b0P + nt * 1024);
            bf16x8 b1 = *(const bf16x8*)(b1P + nt * 1024);
            #pragma unroll
            for (int mt = 0; mt < 4; ++mt) {
                // swapped: D[code][token]
                acc[mt][nt] = __builtin_amdgcn_mfma_f32_16x16x32_bf16(b0, a0[mt], acc[mt][nt], 0, 0, 0);
                acc[mt][nt] = __builtin_amdgcn_mfma_f32_16x16x32_bf16(b1, a1[mt], acc[mt][nt], 0, 0, 0);
            }
        }
    }

    // tiles are dead from here; re-use for the cross-wave reduce arrays
    __syncthreads();
    float* smB = (float*)tiles;            // [2][128]
    int*   smI = (int*)(tiles + 1024);     // [2][128]
    float* smS = (float*)(tiles + 2048);   // [2][128]

    // epilogue: token = wy*64 + mt*16 + frow (C-col), code = n0 + wx*64 +
    // nt*16 + fq*4 + r (C-row). Per-token top-2 of val = esq[code] - 2*dot.
    float eqv[16];
    #pragma unroll
    for (int nt = 0; nt < 4; ++nt) {
        float4 t = *(const float4*)&esq[n0 + wx * 64 + nt * 16 + fq * 4];
        eqv[nt * 4 + 0] = t.x; eqv[nt * 4 + 1] = t.y;
        eqv[nt * 4 + 2] = t.z; eqv[nt * 4 + 3] = t.w;
    }

    #pragma unroll
    for (int mt = 0; mt < 4; ++mt) {
        float b = 3.4e38f, s = 3.4e38f;
        int bi = 0;
        #pragma unroll
        for (int nt = 0; nt < 4; ++nt) {
            #pragma unroll
            for (int r = 0; r < 4; ++r) {
                float v = fmaf(-2.0f, acc[mt][nt][r], eqv[nt * 4 + r]);
                int c = n0 + wx * 64 + nt * 16 + fq * 4 + r;  // monotone in (nt,r)
                if (v < b) { s = b; b = v; bi = c; }
                else if (v < s) s = v;
            }
        }
        #pragma unroll
        for (int o = 16; o < 64; o <<= 1) {      // merge the 4 fq groups
            float ob = __shfl_xor(b, o, 64);
            int   oi = __shfl_xor(bi, o, 64);
            float os = __shfl_xor(s, o, 64);
            bool take = (ob < b) || (ob == b && oi < bi);
            float keep = take ? b : ob;
            b  = take ? ob : b;
            bi = take ? oi : bi;
            s  = fminf(fminf(s, os), keep);
        }
        if (l < 16) {                            // fq == 0 lanes
            int m_loc = wy * 64 + mt * 16 + l;
            smB[wx * 128 + m_loc] = b;
            smI[wx * 128 + m_loc] = bi;
            smS[wx * 128 + m_loc] = s;
        }
    }
    __syncthreads();
    if (tid < 128) {
        float b0 = smB[tid],       b1 = smB[128 + tid];
        int   i0 = smI[tid],       i1 = smI[128 + tid];
        float s0 = smS[tid],       s1 = smS[128 + tid];
        bool take = (b1 < b0);                 // tie -> wave 0 (lower cols)
        float b = take ? b1 : b0;
        int  bi = take ? i1 : i0;
        float s = fminf(fminf(s0, s1), take ? b0 : b1);
        size_t e = (size_t)(m0 + tid) * NBLK_N + blockIdx.y;   // [row][block]
        candV[e] = b; candI[e] = bi; candS[e] = s;
    }
}

// ---------------------------------------------------------------------------
// post: fused reduce + window-rescue + assign. ONE wave per row (4096 blocks
// for TLP). Lane e holds block-e candidates via a coalesced 256B load of the
// [row][block] cand arrays. Packed-u64 min butterfly gives best with lowest-
// index tie-break (== reference argmin semantics). second = min over lanes of
// (bestlane ? candS : candV). Flagged rows (gap < W) window-rescue inline;
// deep blocks (candS < bound) rescan 128 codes batched 4-wide for ILP. No
// atomics/flag indirection for the rescue: the wave owns its row. X row is
// loaded once and reused for the exact dot and the STE quantize write.
__global__ __launch_bounds__(256) void post_kernel(
    const float* __restrict__ X, const float* __restrict__ E,
    const float* __restrict__ esq,
    const float* __restrict__ candV, const int* __restrict__ candI,
    const float* __restrict__ candS,
    float* __restrict__ out_q, float* __restrict__ out_codes,
    float* __restrict__ counts, float* __restrict__ sums)
{
    const int lane = threadIdx.x & 63;
    const int row  = blockIdx.x * 4 + (threadIdx.x >> 6);

    float bv = candV[(size_t)row * NBLK_N + lane];
    float bs = candS[(size_t)row * NBLK_N + lane];
    int   bi = candI[(size_t)row * NBLK_N + lane];

    u64 pk = ((u64)f2key(bv) << 32) | (unsigned)bi;
    u64 m = pk;
    #pragma unroll
    for (int o = 1; o < 64; o <<= 1) {
        u64 other = __shfl_xor(m, o, 64);
        m = (other < m) ? other : m;
    }
    float best = key2f((unsigned)(m >> 32));
    int   code = (int)(unsigned)(m & 0xFFFFFFFFull);

    float sec = (pk == m) ? bs : bv;     // bestlane unique (pk has index)
    #pragma unroll
    for (int o = 1; o < 64; o <<= 1) sec = fminf(sec, __shfl_xor(sec, o, 64));

    const float4 x4 = ((const float4*)&X[(size_t)row * DIM])[lane];

    if (sec - best < GAP_EPS) {          // wave-uniform branch
        const float bound = best + GAP_EPS;
        float bestV = 3.4e38f;
        int   bestI = 0x7FFFFFFF;
        // cheap: exact-eval block bests inside the window (incl. code)
        u64 mask = __ballot(bv < bound);
        while (mask) {
            int src = __ffsll((unsigned long long)mask) - 1;
            mask &= mask - 1;
            int c = __shfl(bi, src, 64);
            float4 e4 = ((const float4*)&E[(size_t)c * DIM])[lane];
            float d = x4.x * e4.x + x4.y * e4.y + x4.z * e4.z + x4.w * e4.w;
            #pragma unroll
            for (int o = 1; o < 64; o <<= 1) d += __shfl_xor(d, o, 64);
            float v = fmaf(-2.0f, d, esq[c]);
            if (v < bestV || (v == bestV && c < bestI)) { bestV = v; bestI = c; }
        }
        // deep: block second also in window -> full rescan, 4-wide ILP
        u64 dmask = __ballot(bs < bound);
        while (dmask) {
            int e = __ffsll((unsigned long long)dmask) - 1;
            dmask &= dmask - 1;
            const int c0 = e * BN;
            for (int j = 0; j < BN; j += 4) {
                float4 e0 = ((const float4*)&E[(size_t)(c0 + j + 0) * DIM])[lane];
                float4 e1 = ((const float4*)&E[(size_t)(c0 + j + 1) * DIM])[lane];
                float4 e2 = ((const float4*)&E[(size_t)(c0 + j + 2) * DIM])[lane];
                float4 e3 = ((const float4*)&E[(size_t)(c0 + j + 3) * DIM])[lane];
                float d0 = x4.x * e0.x + x4.y * e0.y + x4.z * e0.z + x4.w * e0.w;
                float d1 = x4.x * e1.x + x4.y * e1.y + x4.z * e1.z + x4.w * e1.w;
                float d2 = x4.x * e2.x + x4.y * e2.y + x4.z * e2.z + x4.w * e2.w;
                float d3 = x4.x * e3.x + x4.y * e3.y + x4.z * e3.z + x4.w * e3.w;
                #pragma unroll
                for (int o = 1; o < 64; o <<= 1) {
                    d0 += __shfl_xor(d0, o, 64);
                    d1 += __shfl_xor(d1, o, 64);
                    d2 += __shfl_xor(d2, o, 64);
                    d3 += __shfl_xor(d3, o, 64);
                }
                float v0 = fmaf(-2.0f, d0, esq[c0 + j + 0]);
                float v1 = fmaf(-2.0f, d1, esq[c0 + j + 1]);
                float v2 = fmaf(-2.0f, d2, esq[c0 + j + 2]);
                float v3 = fmaf(-2.0f, d3, esq[c0 + j + 3]);
                if (v0 < bestV || (v0 == bestV && c0 + j + 0 < bestI)) { bestV = v0; bestI = c0 + j + 0; }
                if (v1 < bestV || (v1 == bestV && c0 + j + 1 < bestI)) { bestV = v1; bestI = c0 + j + 1; }
                if (v2 < bestV || (v2 == bestV && c0 + j + 2 < bestI)) { bestV = v2; bestI = c0 + j + 2; }
                if (v3 < bestV || (v3 == bestV && c0 + j + 3 < bestI)) { bestV = v3; bestI = c0 + j + 3; }
            }
        }
        code = bestI;
    }

    // assign: codes, STE quantize, EMA scatter
    if (lane == 0) {
        out_codes[row] = (float)code;
        atomicAdd(&counts[code], 1.0f);
    }
    float4 e4 = ((const float4*)&E[(size_t)code * DIM])[lane];
    float4 q;
    q.x = x4.x + (e4.x - x4.x);
    q.y = x4.y + (e4.y - x4.y);
    q.z = x4.z + (e4.z - x4.z);
    q.w = x4.w + (e4.w - x4.w);
    ((float4*)&out_q[(size_t)row * DIM])[lane] = q;
    float* s = &sums[(size_t)code * DIM + lane * 4];
    atomicAdd(s + 0, x4.x);
    atomicAdd(s + 1, x4.y);
    atomicAdd(s + 2, x4.z);
    atomicAdd(s + 3, x4.w);
}

// ---------------------------------------------------------------------------
__global__ __launch_bounds__(256) void finalize_kernel(
    const float* __restrict__ cs, const float* __restrict__ ea,
    const float* __restrict__ counts, const float* __restrict__ sums,
    float* __restrict__ out_embed, float* __restrict__ out_cs,
    float* __restrict__ out_ea)
{
    int vd = blockIdx.x * 256 + threadIdx.x;
    int v = vd >> 8, d = vd & 255;
    float cnt = counts[v];
    float ncs = cs[v] * 0.99f + cnt * 0.01f;
    float cb  = sums[vd] * (1.0f / 2048.0f);
    float nea = ea[vd] * 0.99f + cb * 0.01f;
    out_ea[vd] = nea;
    out_embed[vd] = nea / (ncs + 1e-5f);
    if (d == 0) out_cs[v] = ncs;
}

// ---------------------------------------------------------------------------
extern "C" void kernel_launch(void* const* d_in, const int* in_sizes, int n_in,
                              void* d_out, int out_size, void* d_ws, size_t ws_size,
                              hipStream_t stream)
{
    const float* input     = (const float*)d_in[0];
    const float* embed     = (const float*)d_in[1];
    const float* cluster   = (const float*)d_in[2];
    const float* embed_avg = (const float*)d_in[3];

    float* out = (float*)d_out;
    float* ws  = (float*)d_ws;

    float* esq      = ws + WS_ESQ;
    float* candV    = ws + WS_CANDV;
    int*   candI    = (int*)(ws + WS_CANDI);
    float* candS    = ws + WS_CANDS;
    u16*   Xhi      = (u16*)(ws + WS_XHI);
    u16*   Ehi      = (u16*)(ws + WS_EHI);
    float* counts   = ws + WS_COUNTS;
    float* sums     = ws + WS_SUMS;

    hipMemsetAsync((char*)d_ws + WS_ZERO_OFF_BYTES, 0, WS_ZERO_BYTES, stream);

    prep_kernel<<<(M_TOK + VOC) / 4, 256, 0, stream>>>(
        input, embed, Xhi, Ehi, esq);

    dim3 g1(M_TOK / BM, VOC / BN);
    mfma_argmin_kernel<<<g1, 256, 0, stream>>>(
        Xhi, Ehi, esq, candV, candI, candS);

    post_kernel<<<M_TOK / 4, 256, 0, stream>>>(
        input, embed, esq, candV, candI, candS,
        out + OUT_Q, out + OUT_C, counts, sums);

    finalize_kernel<<<(VOC * DIM) / 256, 256, 0, stream>>>(
        cluster, embed_avg, counts, sums,
        out + OUT_NE, out + OUT_NCS, out + OUT_NEA);
}